// Round 4
// baseline (1635.675 us; speedup 1.0000x reference)
//
#include <hip/hip_runtime.h>
#include <stdint.h>
#include <stdio.h>

// ---------- problem constants ----------
#define NNODES 6720
#define NEDGES 53760
#define NGRAPH 16
#define INDIM  2048
#define HEADS1 4
#define C1DIM  1024
#define D1     4096      // HEADS1*C1DIM
#define C2DIM  64
#define N2     320       // 5*C2: q|k|v|skip|gat
#define OUTDIM 18

typedef unsigned short u16;
typedef unsigned int   u32;

__device__ __forceinline__ float b2f(u16 u) {
  union { float f; u32 u; } v; v.u = ((u32)u) << 16; return v.f;
}
__device__ __forceinline__ u16 f2b(float f) {
  union { float f; u32 u; } v; v.f = f;
  u32 r = v.u + 0x7FFFu + ((v.u >> 16) & 1u);
  return (u16)(r >> 16);
}
__device__ __forceinline__ float ldf(const void* p, long i, int isf) {
  return isf ? ((const float*)p)[i] : b2f(((const u16*)p)[i]);
}

typedef __attribute__((ext_vector_type(8))) short bf16x8;  // 8 bf16 = 4 VGPRs
typedef __attribute__((ext_vector_type(4))) float f32x4;

__device__ __forceinline__ void gld_lds16(const u16* g, u16* l) {
  __builtin_amdgcn_global_load_lds((const __attribute__((address_space(1))) void*)g,
                                   (__attribute__((address_space(3))) void*)l, 16, 0, 0);
}

// ---------- runtime dtype detection (1 = f32 inputs, 0 = bf16 inputs) ----------
__global__ void detect_dtype(const u16* __restrict__ x, int* flag) {
  __shared__ int cnt;
  if (threadIdx.x == 0) cnt = 0;
  __syncthreads();
  int c = 0;
  for (int i = threadIdx.x; i < 4096; i += 256) {
    u16 u = x[2 * i];
    int e = (u >> 7) & 0xFF;
    if (e >= 118 && e <= 135) c++;
  }
  atomicAdd(&cnt, c);
  __syncthreads();
  if (threadIdx.x == 0) *flag = (cnt > 2048) ? 0 : 1;
}

// ---------- generic convert-to-bf16 (grid-stride) ----------
__global__ void conv_any(const void* __restrict__ src, u16* __restrict__ dst,
                         long n, const int* __restrict__ flag) {
  long i = (long)blockIdx.x * 256 + threadIdx.x;
  long stride = (long)gridDim.x * 256;
  int isf = *flag;
  if (isf) {
    const float* s = (const float*)src;
    for (long j = i; j < n; j += stride) dst[j] = f2b(s[j]);
  } else {
    const u16* s = (const u16*)src;
    for (long j = i; j < n; j += stride) dst[j] = s[j];
  }
}

// ---------- fused small conversions: one block per tensor ----------
#define NSMALL 13
struct SmallConv {
  const void* src[NSMALL];
  u16*        dst[NSMALL];
  int         n[NSMALL];
};
__global__ void conv_small(SmallConv sc, const int* __restrict__ flag) {
  int b = blockIdx.x;
  int isf = *flag;
  const void* s = sc.src[b];
  u16* d = sc.dst[b];
  int n = sc.n[b];
  if (isf) {
    const float* sf = (const float*)s;
    for (int i = threadIdx.x; i < n; i += 256) d[i] = f2b(sf[i]);
  } else {
    const u16* sb = (const u16*)s;
    for (int i = threadIdx.x; i < n; i += 256) d[i] = sb[i];
  }
}

// ---------- weight packing: transpose [K,Ncols] (f32 or bf16) -> dst[Ncols,K] bf16 ----------
__global__ __launch_bounds__(256) void transpose_any(const void* __restrict__ src,
                                                     u16* __restrict__ dst,
                                                     int K, int Ncols,
                                                     const int* __restrict__ flag) {
  __shared__ u16 tile[32][33];
  int isf = *flag;
  int tx = threadIdx.x & 31, ty = threadIdx.x >> 5;   // 32 x 8
  int c0 = blockIdx.x * 32, r0 = blockIdx.y * 32;
  if (isf) {
    const float* s = (const float*)src;
    #pragma unroll
    for (int i = 0; i < 32; i += 8)
      tile[ty + i][tx] = f2b(s[(long)(r0 + ty + i) * Ncols + c0 + tx]);
  } else {
    const u16* s = (const u16*)src;
    #pragma unroll
    for (int i = 0; i < 32; i += 8)
      tile[ty + i][tx] = s[(long)(r0 + ty + i) * Ncols + c0 + tx];
  }
  __syncthreads();
  #pragma unroll
  for (int i = 0; i < 32; i += 8)
    dst[(long)(c0 + ty + i) * K + r0 + tx] = tile[tx][ty + i];
}

// bias1 layout: [0:4096)=bq1 [4096:8192)=bk1 [8192:12288)=bv1 [12288:16384)=bs1 [16384:20480)=0
__global__ void pack_bias(const void* bq1, const void* bk1, const void* bv1, const void* bs1,
                          const void* bq2, const void* bk2, const void* bv2, const void* bs2,
                          float* bias1, float* bias2, const int* flag) {
  int isf = *flag;
  int i = blockIdx.x * 256 + threadIdx.x;
  if (i < 20480) {
    float v = 0.f;
    if (i < 4096) v = ldf(bq1, i, isf);
    else if (i < 8192)  v = ldf(bk1, i - 4096, isf);
    else if (i < 12288) v = ldf(bv1, i - 8192, isf);
    else if (i < 16384) v = ldf(bs1, i - 12288, isf);
    bias1[i] = v;
  } else if (i < 20480 + N2) {
    int j = i - 20480; float v = 0.f;
    if (j < 64) v = ldf(bq2, j, isf);
    else if (j < 128) v = ldf(bk2, j - 64, isf);
    else if (j < 192) v = ldf(bv2, j - 128, isf);
    else if (j < 256) v = ldf(bs2, j - 192, isf);
    bias2[j] = v;
  }
}

// ---------- GEMM 256x256 tile, 4-deep LDS ring, counted vmcnt pipeline ----------
// C = A[M,K] * BT[N,K]^T + bias.  K multiple of 32, K/32 >= 3.  512 threads = 8 waves (2M x 4N),
// per-wave output 128x64 -> acc[8][4], 32 MFMA per K-step per wave (vs 16 at 128^2: 2x more
// matrix work per barrier, same verified swizzle/addressing patterns scaled up).
// DEFAULT block order: gridDim.x in {32,16} is %8==0 -> round-robin dispatch pins bx%8 per XCD,
// so each XCD's B-panels (4x1MB) stay L2-resident (R1 lesson: custom swizzle destroyed this).
// LDS col-group XOR-swizzle (verified 0-conflict at 128^2): phys_cg = logical_cg ^ ((row>>1)&3).
// Ring-4 (128 KiB LDS, 1 block/CU — 128 KiB/wg is the verified m201-template geometry on
// gfx950): per K-tile t: s_waitcnt vmcnt(8); s_barrier; STAGE(t+3); ds_read frags(buf t&3);
// 32 MFMA.  vmcnt(8)=2 tiles in flight across the barrier, never 0 in the main loop.
// STAGE(t+3) overwrites buf (t-1)&3 whose readers all finished before this barrier.
__global__ __launch_bounds__(512) void gemm_bt_256(const u16* __restrict__ A,
                                                   const u16* __restrict__ BT,
                                                   const float* __restrict__ bias,
                                                   u16* __restrict__ C,
                                                   int M, int N, int K) {
  __shared__ u16 As[4][256 * 32];   // 4 x 16 KB
  __shared__ u16 Bs[4][256 * 32];   // 4 x 16 KB  (total 128 KB)

  const int tid = threadIdx.x, lane = tid & 63, wave = tid >> 6;
  const int m0 = blockIdx.y * 256, n0 = blockIdx.x * 256;
  const int wr = wave >> 2, wc = wave & 3;          // 2 x 4 wave grid

  // staging: issue0 rows 0..127 (row = tid>>2), issue1 rows 128..255
  const int srow = tid >> 2, scp = tid & 3;
  const int scl8 = (scp ^ ((srow >> 1) & 3)) * 8;   // swizzled logical col-group
  int ar0 = m0 + srow;        if (ar0 >= M) ar0 = M - 1;
  int ar1 = m0 + srow + 128;  if (ar1 >= M) ar1 = M - 1;
  const u16* ag0 = A + (long)ar0 * K + scl8;
  const u16* ag1 = A + (long)ar1 * K + scl8;
  const u16* bg0 = BT + (long)(n0 + srow) * K + scl8;
  const u16* bg1 = BT + (long)(n0 + srow + 128) * K + scl8;

  f32x4 acc[8][4];
  #pragma unroll
  for (int i = 0; i < 8; i++)
    #pragma unroll
    for (int j = 0; j < 4; j++) { f32x4 z = {0.f, 0.f, 0.f, 0.f}; acc[i][j] = z; }

  // fragment-read addressing (same swizzle as staging; row bases are multiples of 64,
  // so (row>>1)&3 depends only on fr — verified at 128^2)
  const int fr = lane & 15, q = lane >> 4;
  const int fq = (q ^ ((fr >> 1) & 3)) * 8;
  const int aoff = (wr * 128 + fr) * 32 + fq;
  const int boff = (wc * 64 + fr) * 32 + fq;

  const int NT = K >> 5;                            // K/32 tiles (>= 3)

  auto STAGE = [&](int t, int b) {
    const long k0 = (long)t * 32;
    gld_lds16(ag0 + k0, &As[b][(size_t)tid * 8]);
    gld_lds16(ag1 + k0, &As[b][4096 + (size_t)tid * 8]);
    gld_lds16(bg0 + k0, &Bs[b][(size_t)tid * 8]);
    gld_lds16(bg1 + k0, &Bs[b][4096 + (size_t)tid * 8]);
  };

  // prologue: tiles 0,1,2 in flight (12 per-wave vm ops)
  STAGE(0, 0); STAGE(1, 1); STAGE(2, 2);

  int cur = 0, nxt = 3;                             // buf of tile t; buf for tile t+3
  for (int t = 0; t < NT; ++t) {
    if (t < NT - 2) {
      asm volatile("s_waitcnt vmcnt(8)\n\ts_barrier" ::: "memory");
    } else if (t == NT - 2) {
      asm volatile("s_waitcnt vmcnt(4)\n\ts_barrier" ::: "memory");
    } else {
      asm volatile("s_waitcnt vmcnt(0)\n\ts_barrier" ::: "memory");
    }
    if (t + 3 < NT) STAGE(t + 3, nxt);

    const u16* ab = &As[cur][0];
    const u16* bb = &Bs[cur][0];
    bf16x8 af[8], bfv[4];
    #pragma unroll
    for (int i = 0; i < 8; i++) af[i]  = *(const bf16x8*)(ab + aoff + i * 512);
    #pragma unroll
    for (int j = 0; j < 4; j++) bfv[j] = *(const bf16x8*)(bb + boff + j * 512);

    #pragma unroll
    for (int i = 0; i < 8; i++)
      #pragma unroll
      for (int j = 0; j < 4; j++)
        acc[i][j] = __builtin_amdgcn_mfma_f32_16x16x32_bf16(af[i], bfv[j], acc[i][j], 0, 0, 0);

    cur = (cur + 1) & 3;
    nxt = (nxt + 1) & 3;
  }

  const int q4 = (lane >> 4) * 4, cl = lane & 15;
  #pragma unroll
  for (int i = 0; i < 8; i++)
    #pragma unroll
    for (int r = 0; r < 4; r++) {
      int row = m0 + wr * 128 + i * 16 + q4 + r;
      if (row < M) {
        #pragma unroll
        for (int j = 0; j < 4; j++) {
          int col = n0 + wc * 64 + j * 16 + cl;
          C[(long)row * N + col] = f2b(acc[i][j][r] + bias[col]);
        }
      }
    }
}

// ---------- merged layer-2 GEMM: 5 n-tiles of 64, M=6720, K=4096, BK=64 ----------
// nt<4: A=h1 (t2 q|k|v|skip); nt==4: A=z1 (g2). Swizzle: phys_cg = logical ^ (row&7).
__global__ __launch_bounds__(256) void gemm2_64(const u16* __restrict__ h1,
                                                const u16* __restrict__ z1,
                                                const u16* __restrict__ wt2,
                                                const float* __restrict__ bias2,
                                                u16* __restrict__ y2) {
  __shared__ u16 As[64 * 64];
  __shared__ u16 Bs[64 * 64];
  const int nt = blockIdx.x;
  const u16* A = (nt < 4) ? h1 : z1;
  const u16* BT = wt2 + (size_t)nt * 64 * D1;
  const int m0 = blockIdx.y * 64, n0 = nt * 64;
  const int tid = threadIdx.x, lane = tid & 63, wave = tid >> 6;

  const int sr = tid >> 3, cp = tid & 7;
  const int cgl8 = (cp ^ (sr & 7)) * 8;
  const u16* ag0 = A + (long)(m0 + sr) * D1 + cgl8;
  const u16* ag1 = ag0 + (long)32 * D1;
  const u16* bg0 = BT + (long)sr * D1 + cgl8;
  const u16* bg1 = bg0 + (long)32 * D1;
  u16* al0 = As + tid * 8;  u16* al1 = As + 2048 + tid * 8;
  u16* bl0 = Bs + tid * 8;  u16* bl1 = Bs + 2048 + tid * 8;

  f32x4 acc[4];
  #pragma unroll
  for (int j = 0; j < 4; j++) { f32x4 z = {0.f, 0.f, 0.f, 0.f}; acc[j] = z; }

  const int fr = lane & 15, q = lane >> 4;
  const int x0 = ((q)     ^ (fr & 7)) * 8;   // kk=0 phys col-group
  const int x1 = ((4 + q) ^ (fr & 7)) * 8;   // kk=1
  const u16* apA = As + (wave * 16 + fr) * 64;

  for (int k0 = 0; k0 < D1; k0 += 64) {
    __syncthreads();
    gld_lds16(ag0 + k0, al0);
    gld_lds16(ag1 + k0, al1);
    gld_lds16(bg0 + k0, bl0);
    gld_lds16(bg1 + k0, bl1);
    __syncthreads();
    bf16x8 a0 = *(const bf16x8*)(apA + x0);
    bf16x8 a1 = *(const bf16x8*)(apA + x1);
    #pragma unroll
    for (int j = 0; j < 4; j++) {
      bf16x8 b0 = *(const bf16x8*)(Bs + (j * 16 + fr) * 64 + x0);
      acc[j] = __builtin_amdgcn_mfma_f32_16x16x32_bf16(a0, b0, acc[j], 0, 0, 0);
    }
    #pragma unroll
    for (int j = 0; j < 4; j++) {
      bf16x8 b1 = *(const bf16x8*)(Bs + (j * 16 + fr) * 64 + x1);
      acc[j] = __builtin_amdgcn_mfma_f32_16x16x32_bf16(a1, b1, acc[j], 0, 0, 0);
    }
  }
  const int q4 = (lane >> 4) * 4, cl = lane & 15;
  #pragma unroll
  for (int j = 0; j < 4; j++)
    #pragma unroll
    for (int r = 0; r < 4; r++) {
      int row = m0 + wave * 16 + q4 + r;
      int col = n0 + j * 16 + cl;
      y2[(long)row * N2 + col] = f2b(acc[j][r] + bias2[col]);
    }
}

// ---------- CSR build ----------
__global__ void zero_kernel(int* deg, float* f1sum) {
  int i = blockIdx.x * 256 + threadIdx.x;
  if (i < NNODES) deg[i] = 0;
  if (i < NGRAPH * 256) f1sum[i] = 0.f;
}

__global__ void count_deg(const int* __restrict__ ei, int* deg) {
  int e = blockIdx.x * 256 + threadIdx.x;
  if (e < NEDGES) atomicAdd(&deg[ei[NEDGES + e]], 1);
}

__global__ __launch_bounds__(1024) void scan_deg(const int* __restrict__ deg, int* off, int* cur) {
  __shared__ int sh[1024];
  const int t = threadIdx.x;
  const int PER = 7;
  int base = t * PER;
  int loc[PER];
  int sum = 0;
  #pragma unroll
  for (int i = 0; i < PER; i++) {
    int v = (base + i < NNODES) ? deg[base + i] : 0;
    loc[i] = sum; sum += v;
  }
  sh[t] = sum;
  __syncthreads();
  for (int d = 1; d < 1024; d <<= 1) {
    int v = (t >= d) ? sh[t - d] : 0;
    __syncthreads();
    sh[t] += v;
    __syncthreads();
  }
  int prev = (t > 0) ? sh[t - 1] : 0;
  #pragma unroll
  for (int i = 0; i < PER; i++) {
    int idx = base + i;
    if (idx <= NNODES) {
      int v = prev + loc[i];
      off[idx] = v;
      if (idx < NNODES) cur[idx] = v;
    }
  }
}

__global__ void scatter_edges(const int* __restrict__ ei, int* cur,
                              int* esrc, int* edst) {
  int e = blockIdx.x * 256 + threadIdx.x;
  if (e < NEDGES) {
    int s = ei[e], d = ei[NEDGES + e];
    int p = atomicAdd(&cur[d], 1);
    esrc[p] = s; edst[p] = d;
  }
}

// ---------- T1 scores, CSR: block per dst node; q row cached in LDS ----------
__global__ __launch_bounds__(256) void t1_score_csr(const u16* __restrict__ yqk,
                                                    const int* __restrict__ off,
                                                    const int* __restrict__ esrc,
                                                    float* __restrict__ sc) {
  __shared__ float qsh[4096];
  int n = blockIdx.x, tid = threadIdx.x, lane = tid & 63, wave = tid >> 6;
  const u16* qr = yqk + (long)n * 8192;
  for (int i = tid * 8; i < 4096; i += 2048) {
    uint4 qa = *(const uint4*)(qr + i);
    const u16* qs = (const u16*)&qa;
    #pragma unroll
    for (int j = 0; j < 8; j++) qsh[i + j] = b2f(qs[j]);
  }
  __syncthreads();
  int p0 = off[n], p1 = off[n + 1];
  for (int p = p0 + wave; p < p1; p += 4) {
    const u16* k = yqk + (long)esrc[p] * 8192 + 4096;
    float dot[HEADS1];
    #pragma unroll
    for (int h = 0; h < HEADS1; h++) dot[h] = 0.f;
    #pragma unroll
    for (int h = 0; h < HEADS1; h++) {
      #pragma unroll
      for (int c = 0; c < 2; c++) {
        int idx = h * C1DIM + c * 512 + lane * 8;
        uint4 ka = *(const uint4*)(k + idx);
        const u16* ks = (const u16*)&ka;
        #pragma unroll
        for (int i = 0; i < 8; i++) dot[h] += qsh[idx + i] * b2f(ks[i]);
      }
    }
    #pragma unroll
    for (int h = 0; h < HEADS1; h++) {
      float v = dot[h];
      #pragma unroll
      for (int o = 32; o > 0; o >>= 1) v += __shfl_xor(v, o, 64);
      if (lane == 0) sc[(long)p * HEADS1 + h] = v * (1.0f / 32.0f);
    }
  }
}

// ---------- segment softmax over dst (thread per node*head), in-place ----------
__global__ void seg_softmax(const int* __restrict__ off, float* __restrict__ sc,
                            float* __restrict__ selfsc, int heads, int useSelf) {
  int i = blockIdx.x * 256 + threadIdx.x;
  if (i >= NNODES * heads) return;
  int n = i / heads, h = i - n * heads;
  int p0 = off[n], p1 = off[n + 1];
  float m = -3.4e38f;
  for (int p = p0; p < p1; p++) m = fmaxf(m, sc[p * heads + h]);
  if (useSelf) m = fmaxf(m, selfsc[i]);
  float den = 0.f;
  for (int p = p0; p < p1; p++) {
    float e = __expf(sc[p * heads + h] - m);
    sc[p * heads + h] = e; den += e;
  }
  float selfe = 0.f;
  if (useSelf) { selfe = __expf(selfsc[i] - m); den += selfe; }
  float inv = 1.0f / (den + 1e-16f);
  for (int p = p0; p < p1; p++) sc[p * heads + h] *= inv;
  if (useSelf) selfsc[i] = selfe * inv;
}

// ---------- T1 aggregate: yvs rows [v(4096) | skip(4096)], stride 8192 ----------
__global__ __launch_bounds__(256) void t1_agg(const u16* __restrict__ yvs,
                                              const int* __restrict__ off,
                                              const int* __restrict__ esrc,
                                              const float* __restrict__ alpha,
                                              u16* __restrict__ h1) {
  int n = blockIdx.x, t = threadIdx.x, h = t >> 6;
  int p0 = off[n], p1 = off[n + 1];
  float acc[16];
  #pragma unroll
  for (int i = 0; i < 16; i++) acc[i] = 0.f;
  for (int p = p0; p < p1; p++) {
    float a = alpha[p * 4 + h];
    const u16* v = yvs + (long)esrc[p] * 8192 + t * 16;
    uint4 v0 = *(const uint4*)(v);
    uint4 v1 = *(const uint4*)(v + 8);
    const u16* s0 = (const u16*)&v0; const u16* s1 = (const u16*)&v1;
    #pragma unroll
    for (int i = 0; i < 8; i++) acc[i] += a * b2f(s0[i]);
    #pragma unroll
    for (int i = 0; i < 8; i++) acc[8 + i] += a * b2f(s1[i]);
  }
  const u16* sk = yvs + (long)n * 8192 + 4096 + t * 16;
  uint4 k0 = *(const uint4*)(sk); uint4 k1 = *(const uint4*)(sk + 8);
  const u16* ks0 = (const u16*)&k0; const u16* ks1 = (const u16*)&k1;
  u16 outv[16];
  #pragma unroll
  for (int i = 0; i < 8; i++) outv[i] = f2b(fmaxf(acc[i] + b2f(ks0[i]), 0.f));
  #pragma unroll
  for (int i = 0; i < 8; i++) outv[8 + i] = f2b(fmaxf(acc[8 + i] + b2f(ks1[i]), 0.f));
  *(uint4*)(h1 + (long)n * D1 + t * 16) = *(uint4*)outv;
  *(uint4*)(h1 + (long)n * D1 + t * 16 + 8) = *(uint4*)(outv + 8);
}

// ---------- GAT1: per-node attention dots (gat compact [N,4096]) ----------
__global__ __launch_bounds__(256) void g1_dots(const u16* __restrict__ gat,
                                               const u16* __restrict__ a_src,
                                               const u16* __restrict__ a_dst,
                                               float* __restrict__ es, float* __restrict__ ed) {
  int n = blockIdx.x;
  int h = threadIdx.x >> 6, lane = threadIdx.x & 63;
  const u16* hr = gat + (long)n * D1 + h * C1DIM;
  const u16* as = a_src + h * C1DIM;
  const u16* ad = a_dst + h * C1DIM;
  float s1 = 0.f, s2 = 0.f;
  #pragma unroll
  for (int c = 0; c < 2; c++) {
    int idx = c * 512 + lane * 8;
    uint4 hv = *(const uint4*)(hr + idx);
    uint4 av = *(const uint4*)(as + idx);
    uint4 dv = *(const uint4*)(ad + idx);
    const u16* hs = (const u16*)&hv; const u16* a1 = (const u16*)&av; const u16* d1 = (const u16*)&dv;
    #pragma unroll
    for (int i = 0; i < 8; i++) {
      float x = b2f(hs[i]);
      s1 += x * b2f(a1[i]); s2 += x * b2f(d1[i]);
    }
  }
  #pragma unroll
  for (int o = 32; o > 0; o >>= 1) { s1 += __shfl_xor(s1, o, 64); s2 += __shfl_xor(s2, o, 64); }
  if (lane == 0) { es[n * 4 + h] = s1; ed[n * 4 + h] = s2; }
}

// ---------- GAT scores (edges + self loops), leaky relu 0.2 ----------
__global__ void gat_score(const int* __restrict__ esrc, const int* __restrict__ edst,
                          const float* __restrict__ es, const float* __restrict__ ed,
                          float* __restrict__ sc, float* __restrict__ selfsc, int heads) {
  int i = blockIdx.x * 256 + threadIdx.x;
  int ne = NEDGES * heads;
  if (i < ne) {
    int p = i / heads, h = i - p * heads;
    float v = es[esrc[p] * heads + h] + ed[edst[p] * heads + h];
    sc[i] = (v > 0.f) ? v : 0.2f * v;
  } else {
    int j = i - ne;
    if (j < NNODES * heads) {
      float v = es[j] + ed[j];
      selfsc[j] = (v > 0.f) ? v : 0.2f * v;
    }
  }
}

// ---------- GAT1 aggregate (gat compact [N,4096]) -> z1 ----------
__global__ __launch_bounds__(256) void g1_agg(const u16* __restrict__ gat,
                                              const int* __restrict__ off,
                                              const int* __restrict__ esrc,
                                              const float* __restrict__ alpha,
                                              const float* __restrict__ selfa,
                                              const u16* __restrict__ bias,
                                              u16* __restrict__ z1) {
  int n = blockIdx.x, t = threadIdx.x, h = t >> 6;
  int p0 = off[n], p1 = off[n + 1];
  float acc[16];
  #pragma unroll
  for (int i = 0; i < 16; i++) acc[i] = 0.f;
  for (int p = p0; p < p1; p++) {
    float a = alpha[p * 4 + h];
    const u16* v = gat + (long)esrc[p] * D1 + t * 16;
    uint4 v0 = *(const uint4*)(v);
    uint4 v1 = *(const uint4*)(v + 8);
    const u16* s0 = (const u16*)&v0; const u16* s1 = (const u16*)&v1;
    #pragma unroll
    for (int i = 0; i < 8; i++) acc[i] += a * b2f(s0[i]);
    #pragma unroll
    for (int i = 0; i < 8; i++) acc[8 + i] += a * b2f(s1[i]);
  }
  {
    float a = selfa[n * 4 + h];
    const u16* v = gat + (long)n * D1 + t * 16;
    uint4 v0 = *(const uint4*)(v);
    uint4 v1 = *(const uint4*)(v + 8);
    const u16* s0 = (const u16*)&v0; const u16* s1 = (const u16*)&v1;
    #pragma unroll
    for (int i = 0; i < 8; i++) acc[i] += a * b2f(s0[i]);
    #pragma unroll
    for (int i = 0; i < 8; i++) acc[8 + i] += a * b2f(s1[i]);
  }
  u16 outv[16];
  #pragma unroll
  for (int i = 0; i < 16; i++) outv[i] = f2b(fmaxf(acc[i] + b2f(bias[t * 16 + i]), 0.f));
  *(uint4*)(z1 + (long)n * D1 + t * 16) = *(uint4*)outv;
  *(uint4*)(z1 + (long)n * D1 + t * 16 + 8) = *(uint4*)(outv + 8);
}

// ---------- layer-2 (dim 64) kernels: wave per edge / node; y2 stride 320 ----------
__global__ __launch_bounds__(256) void t2_score(const u16* __restrict__ y2,
                                                const int* __restrict__ esrc,
                                                const int* __restrict__ edst,
                                                float* __restrict__ sc) {
  int w = (blockIdx.x * 256 + threadIdx.x) >> 6, lane = threadIdx.x & 63;
  if (w >= NEDGES) return;
  float q = b2f(y2[(long)edst[w] * N2 + lane]);
  float k = b2f(y2[(long)esrc[w] * N2 + C2DIM + lane]);
  float v = q * k;
  #pragma unroll
  for (int o = 32; o > 0; o >>= 1) v += __shfl_xor(v, o, 64);
  if (lane == 0) sc[w] = v * 0.125f;
}

__global__ __launch_bounds__(256) void t2_agg(const u16* __restrict__ y2,
                                              const int* __restrict__ off,
                                              const int* __restrict__ esrc,
                                              const float* __restrict__ alpha,
                                              float* __restrict__ sn) {
  int n = (blockIdx.x * 256 + threadIdx.x) >> 6, lane = threadIdx.x & 63;
  if (n >= NNODES) return;
  int p0 = off[n], p1 = off[n + 1];
  float acc = 0.f;
  for (int p = p0; p < p1; p++)
    acc += alpha[p] * b2f(y2[(long)esrc[p] * N2 + 2 * C2DIM + lane]);
  acc += b2f(y2[(long)n * N2 + 3 * C2DIM + lane]);   // skip
  sn[(long)n * C2DIM + lane] = fmaxf(acc, 0.f);
}

__global__ __launch_bounds__(256) void g2_dots(const u16* __restrict__ y2,
                                               const u16* __restrict__ as,
                                               const u16* __restrict__ ad,
                                               float* __restrict__ es, float* __restrict__ ed) {
  int n = (blockIdx.x * 256 + threadIdx.x) >> 6, lane = threadIdx.x & 63;
  if (n >= NNODES) return;
  float x = b2f(y2[(long)n * N2 + 4 * C2DIM + lane]);
  float s1 = x * b2f(as[lane]), s2 = x * b2f(ad[lane]);
  #pragma unroll
  for (int o = 32; o > 0; o >>= 1) { s1 += __shfl_xor(s1, o, 64); s2 += __shfl_xor(s2, o, 64); }
  if (lane == 0) { es[n] = s1; ed[n] = s2; }
}

__global__ __launch_bounds__(256) void g2_agg(const u16* __restrict__ y2,
                                              const int* __restrict__ off,
                                              const int* __restrict__ esrc,
                                              const float* __restrict__ alpha,
                                              const float* __restrict__ selfa,
                                              const u16* __restrict__ bias,
                                              float* __restrict__ sn) {
  int n = (blockIdx.x * 256 + threadIdx.x) >> 6, lane = threadIdx.x & 63;
  if (n >= NNODES) return;
  int p0 = off[n], p1 = off[n + 1];
  float acc = 0.f;
  for (int p = p0; p < p1; p++)
    acc += alpha[p] * b2f(y2[(long)esrc[p] * N2 + 4 * C2DIM + lane]);
  acc += selfa[n] * b2f(y2[(long)n * N2 + 4 * C2DIM + lane]);
  float v = fmaxf(acc + b2f(bias[lane]), 0.f);
  sn[(long)n * C2DIM + lane] += v;
}

// ---------- MLP head ----------
#define FCHUNK 210   // 26880 = 128 * 210
__global__ __launch_bounds__(256) void fc1_partial(const float* __restrict__ sn,
                                                   const void* __restrict__ w,
                                                   const int* __restrict__ flag,
                                                   float* __restrict__ f1sum) {
  __shared__ float sl[16 * FCHUNK];
  int k0 = blockIdx.x * FCHUNK;
  int t = threadIdx.x;
  int isf = *flag;
  for (int idx = t; idx < 16 * FCHUNK; idx += 256) {
    int g = idx / FCHUNK, kk = idx - g * FCHUNK;
    sl[idx] = sn[(long)g * 26880 + k0 + kk];
  }
  __syncthreads();
  float acc[16];
  #pragma unroll
  for (int g = 0; g < 16; g++) acc[g] = 0.f;
  if (isf) {
    const float* wf = (const float*)w;
    for (int kk = 0; kk < FCHUNK; kk++) {
      float wv = wf[(long)(k0 + kk) * 256 + t];
      #pragma unroll
      for (int g = 0; g < 16; g++) acc[g] += sl[g * FCHUNK + kk] * wv;
    }
  } else {
    const u16* wb = (const u16*)w;
    for (int kk = 0; kk < FCHUNK; kk++) {
      float wv = b2f(wb[(long)(k0 + kk) * 256 + t]);
      #pragma unroll
      for (int g = 0; g < 16; g++) acc[g] += sl[g * FCHUNK + kk] * wv;
    }
  }
  #pragma unroll
  for (int g = 0; g < 16; g++) atomicAdd(&f1sum[g * 256 + t], acc[g]);
}

__global__ __launch_bounds__(256) void fc_tail(const float* __restrict__ f1sum,
                                               const u16* b1, const u16* w2, const u16* b2,
                                               const u16* w3, const u16* b3,
                                               const u16* w4, const u16* b4,
                                               void* __restrict__ out,
                                               const int* __restrict__ flag) {
  __shared__ float A1[16 * 256];
  __shared__ float A2[16 * 128];
  __shared__ float A3[16 * 64];
  int isf = *flag;
  int t = threadIdx.x;
  for (int i = t; i < 4096; i += 256) A1[i] = fmaxf(f1sum[i] + b2f(b1[i & 255]), 0.f);
  __syncthreads();
  for (int i = t; i < 2048; i += 256) {
    int g = i >> 7, j = i & 127;
    float acc = b2f(b2[j]);
    for (int k = 0; k < 256; k++) acc += A1[g * 256 + k] * b2f(w2[k * 128 + j]);
    A2[i] = fmaxf(acc, 0.f);
  }
  __syncthreads();
  for (int i = t; i < 1024; i += 256) {
    int g = i >> 6, j = i & 63;
    float acc = b2f(b3[j]);
    for (int k = 0; k < 128; k++) acc += A2[g * 128 + k] * b2f(w3[k * 64 + j]);
    A3[i] = fmaxf(acc, 0.f);
  }
  __syncthreads();
  for (int i = t; i < NGRAPH * OUTDIM; i += 256) {
    int g = i / OUTDIM, j = i - g * OUTDIM;
    float acc = b2f(b4[j]);
    for (int k = 0; k < 64; k++) acc += A3[g * 64 + k] * b2f(w4[k * OUTDIM + j]);
    if (isf) ((float*)out)[i] = acc;
    else     ((u16*)out)[i] = f2b(acc);
  }
}

// ---------- host ----------
extern "C" void kernel_launch(void* const* d_in, const int* in_sizes, int n_in,
                              void* d_out, int out_size, void* d_ws, size_t ws_size,
                              hipStream_t stream) {
  const void* x     = d_in[0];
  const int*  ei    = (const int*)d_in[1];
  const void* t1_wq = d_in[2];
  const void* t1_wk = d_in[3];
  const void* t1_wv = d_in[4];
  const void* t1_ws = d_in[5];
  const void* t1_bq = d_in[6];
  const void* t1_bk = d_in[7];
  const void* t1_bv = d_in[8];
  const void* t1_bs = d_in[9];
  const void* t2_wq = d_in[10];
  const void* t2_wk = d_in[11];
  const void* t2_wv = d_in[12];
  const void* t2_ws = d_in[13];
  const void* t2_bq = d_in[14];
  const void* t2_bk = d_in[15];
  const void* t2_bv = d_in[16];
  const void* t2_bs = d_in[17];
  const void* g1_w  = d_in[18];
  const void* g1_as = d_in[19];
  const void* g1_ad = d_in[20];
  const void* g1_b  = d_in[21];
  const void* g2_w  = d_in[22];
  const void* g2_as = d_in[23];
  const void* g2_ad = d_in[24];
  const void* g2_b  = d_in[25];
  const void* fc1_w = d_in[26];
  const void* fc1_b = d_in[27];
  const void* fc2_w = d_in[28];
  const void* fc2_b = d_in[29];
  const void* fc3_w = d_in[30];
  const void* fc3_b = d_in[31];
  const void* fc4_w = d_in[32];
  const void* fc4_b = d_in[33];

  char* wp = (char*)d_ws;
  auto alloc = [&](size_t bytes) {
    char* p = wp; wp += (bytes + 255) & ~(size_t)255; return p;
  };
  u16*   wtSlab = (u16*)  alloc((size_t)8192 * INDIM * 2);       // 33.6 MB, reused per phase
  u16*   wt2    = (u16*)  alloc((size_t)N2 * D1 * 2);            // 2.6 MB
  u16*   yqk    = (u16*)  alloc((size_t)NNODES * 8192 * 2);      // 110 MB, phased
  u16*   h1     = (u16*)  alloc((size_t)NNODES * D1 * 2);        // 55 MB
  u16*   y2     = (u16*)  alloc((size_t)NNODES * N2 * 2);        // 4.3 MB
  u16*   xb     = (u16*)  alloc((size_t)NNODES * INDIM * 2);     // 27.5 MB
  u16*   fc2wb  = (u16*)  alloc((size_t)256 * 128 * 2);
  u16*   fc3wb  = (u16*)  alloc((size_t)128 * 64 * 2);
  u16*   fc4wb  = (u16*)  alloc((size_t)64 * OUTDIM * 2);
  u16*   fb1    = (u16*)  alloc(256 * 2);
  u16*   fb2    = (u16*)  alloc(128 * 2);
  u16*   fb3    = (u16*)  alloc(64 * 2);
  u16*   fb4    = (u16*)  alloc(OUTDIM * 2);
  u16*   g1asb  = (u16*)  alloc(4096 * 2);
  u16*   g1adb  = (u16*)  alloc(4096 * 2);
  u16*   g1bb   = (u16*)  alloc(4096 * 2);
  u16*   g2asb  = (u16*)  alloc(64 * 2);
  u16*   g2adb  = (u16*)  alloc(64 * 2);
  u16*   g2bb   = (u16*)  alloc(64 * 2);
  float* bias1  = (float*)alloc((size_t)20480 * 4);
  float* bias2  = (float*)alloc((size_t)N2 * 4);
  int*   flag   = (int*)  alloc(256);
  int*   deg    = (int*)  alloc((size_t)NNODES * 4);
  int*   off    = (int*)  alloc((size_t)(NNODES + 1) * 4);
  int*   cur    = (int*)  alloc((size_t)NNODES * 4);
  int*   esrc   = (int*)  alloc((size_t)NEDGES * 4);
  int*   edst   = (int*)  alloc((size_t)NEDGES * 4);
  float* scT1   = (float*)alloc((size_t)NEDGES * 4 * 4);
  float* esG1   = (float*)alloc((size_t)NNODES * 4 * 4);
  float* edG1   = (float*)alloc((size_t)NNODES * 4 * 4);
  float* scG1   = (float*)alloc((size_t)NEDGES * 4 * 4);
  float* sfG1   = (float*)alloc((size_t)NNODES * 4 * 4);
  float* scT2   = (float*)alloc((size_t)NEDGES * 4);
  float* scG2   = (float*)alloc((size_t)NEDGES * 4);
  float* sfG2   = (float*)alloc((size_t)NNODES * 4);
  float* es2    = (float*)alloc((size_t)NNODES * 4);
  float* ed2    = (float*)alloc((size_t)NNODES * 4);
  float* sn     = (float*)alloc((size_t)NNODES * C2DIM * 4);
  float* f1sum  = (float*)alloc((size_t)NGRAPH * 256 * 4);

  // aliases into yqk for phase C (exactly fills the buffer, no overlap)
  u16* gat = yqk;                               // [NNODES, 4096] compact
  u16* z1  = yqk + (size_t)NNODES * D1;         // [NNODES, 4096] compact

  size_t need = (size_t)(wp - (char*)d_ws);
  if (ws_size < need) {
    fprintf(stderr, "[GATGT kernel] WORKSPACE TOO SMALL ws=%zu need=%zu\n", ws_size, need);
    return;
  }

  // 0) dtype detection
  detect_dtype<<<1, 256, 0, stream>>>((const u16*)x, flag);

  // 1) init + CSR
  zero_kernel<<<27, 256, 0, stream>>>(deg, f1sum);
  count_deg<<<NEDGES / 256, 256, 0, stream>>>(ei, deg);
  scan_deg<<<1, 1024, 0, stream>>>(deg, off, cur);
  scatter_edges<<<NEDGES / 256, 256, 0, stream>>>(ei, cur, esrc, edst);
  pack_bias<<<82, 256, 0, stream>>>(t1_bq, t1_bk, t1_bv, t1_bs,
                                    t2_bq, t2_bk, t2_bv, t2_bs, bias1, bias2, flag);

  // 2) conversions
  conv_any<<<4096, 256, 0, stream>>>(x, xb, (long)NNODES * INDIM, flag);
  {
    SmallConv sc;
    const void* srcs[NSMALL] = { fc2_w, fc3_w, fc4_w, fc1_b, fc2_b, fc3_b, fc4_b,
                                 g1_as, g1_ad, g1_b, g2_as, g2_ad, g2_b };
    u16* dsts[NSMALL] = { fc2wb, fc3wb, fc4wb, fb1, fb2, fb3, fb4,
                          g1asb, g1adb, g1bb, g2asb, g2adb, g2bb };
    int  ns[NSMALL]   = { 256 * 128, 128 * 64, 64 * OUTDIM, 256, 128, 64, OUTDIM,
                          4096, 4096, 4096, 64, 64, 64 };
    for (int i = 0; i < NSMALL; i++) { sc.src[i] = srcs[i]; sc.dst[i] = dsts[i]; sc.n[i] = ns[i]; }
    conv_small<<<NSMALL, 256, 0, stream>>>(sc, flag);
  }

  // 3) Phase A: yqk = xb @ [wq|wk] + [bq|bk]
  transpose_any<<<dim3(128, 64), 256, 0, stream>>>(t1_wq, wtSlab, INDIM, 4096, flag);
  transpose_any<<<dim3(128, 64), 256, 0, stream>>>(t1_wk, wtSlab + (size_t)4096 * INDIM, INDIM, 4096, flag);
  gemm_bt_256<<<dim3(32, 27), 512, 0, stream>>>(xb, wtSlab, bias1, yqk, NNODES, 8192, INDIM);
  t1_score_csr<<<NNODES, 256, 0, stream>>>(yqk, off, esrc, scT1);
  seg_softmax<<<105, 256, 0, stream>>>(off, scT1, nullptr, 4, 0);

  // 4) Phase B: yqk = xb @ [wv|ws] + [bv|bs]
  transpose_any<<<dim3(128, 64), 256, 0, stream>>>(t1_wv, wtSlab, INDIM, 4096, flag);
  transpose_any<<<dim3(128, 64), 256, 0, stream>>>(t1_ws, wtSlab + (size_t)4096 * INDIM, INDIM, 4096, flag);
  gemm_bt_256<<<dim3(32, 27), 512, 0, stream>>>(xb, wtSlab, bias1 + 8192, yqk, NNODES, 8192, INDIM);
  t1_agg<<<NNODES, 256, 0, stream>>>(yqk, off, esrc, scT1, h1);

  // 5) Phase C: gat = xb @ g1_w; z1 in upper half of yqk
  transpose_any<<<dim3(128, 64), 256, 0, stream>>>(g1_w, wtSlab, INDIM, 4096, flag);
  gemm_bt_256<<<dim3(16, 27), 512, 0, stream>>>(xb, wtSlab, bias1 + 16384, gat, NNODES, 4096, INDIM);
  g1_dots<<<NNODES, 256, 0, stream>>>(gat, g1asb, g1adb, esG1, edG1);
  gat_score<<<(NEDGES * 4 + NNODES * 4 + 255) / 256, 256, 0, stream>>>(
      esrc, edst, esG1, edG1, scG1, sfG1, 4);
  seg_softmax<<<105, 256, 0, stream>>>(off, scG1, sfG1, 4, 1);
  g1_agg<<<NNODES, 256, 0, stream>>>(gat, off, esrc, scG1, sfG1, g1bb, z1);

  // 6) merged layer-2 GEMM: y2 = [h1@t2w(+bias) | z1@g2w]
  {
    const void* srcs2[5] = { t2_wq, t2_wk, t2_wv, t2_ws, g2_w };
    for (int s = 0; s < 5; s++)
      transpose_any<<<dim3(2, 128), 256, 0, stream>>>(
          srcs2[s], wt2 + (size_t)s * 64 * D1, D1, 64, flag);
  }
  gemm2_64<<<dim3(5, NNODES / 64), 256, 0, stream>>>(h1, z1, wt2, bias2, y2);

  // 7) TransformerConv 2
  t2_score<<<NEDGES / 4, 256, 0, stream>>>(y2, esrc, edst, scT2);
  seg_softmax<<<(NNODES + 255) / 256, 256, 0, stream>>>(off, scT2, nullptr, 1, 0);
  t2_agg<<<NNODES / 4, 256, 0, stream>>>(y2, off, esrc, scT2, sn);

  // 8) GATConv 2 (adds into sn)
  g2_dots<<<NNODES / 4, 256, 0, stream>>>(y2, g2asb, g2adb, es2, ed2);
  gat_score<<<(NEDGES + NNODES + 255) / 256, 256, 0, stream>>>(
      esrc, edst, es2, ed2, scG2, sfG2, 1);
  seg_softmax<<<(NNODES + 255) / 256, 256, 0, stream>>>(off, scG2, sfG2, 1, 1);
  g2_agg<<<NNODES / 4, 256, 0, stream>>>(y2, off, esrc, scG2, sfG2, g2bb, sn);

  // 9) MLP head
  fc1_partial<<<128, 256, 0, stream>>>(sn, fc1_w, flag, f1sum);
  fc_tail<<<1, 256, 0, stream>>>(f1sum, fb1, fc2wb, fb2, fc3wb, fb3,
                                 fc4wb, fb4, d_out, flag);
}

// Round 5
// 1472.826 us; speedup vs baseline: 1.1106x; 1.1106x over previous
//
#include <hip/hip_runtime.h>
#include <stdint.h>
#include <stdio.h>

// ---------- problem constants ----------
#define NNODES 6720
#define NEDGES 53760
#define NGRAPH 16
#define INDIM  2048
#define HEADS1 4
#define C1DIM  1024
#define D1     4096      // HEADS1*C1DIM
#define C2DIM  64
#define N2     320       // 5*C2: q|k|v|skip|gat
#define OUTDIM 18
#define SMCAP  256       // max edges per node handled in-LDS (random input max deg ~30)

typedef unsigned short u16;
typedef unsigned int   u32;

__device__ __forceinline__ float b2f(u16 u) {
  union { float f; u32 u; } v; v.u = ((u32)u) << 16; return v.f;
}
__device__ __forceinline__ u16 f2b(float f) {
  union { float f; u32 u; } v; v.f = f;
  u32 r = v.u + 0x7FFFu + ((v.u >> 16) & 1u);
  return (u16)(r >> 16);
}
__device__ __forceinline__ float ldf(const void* p, long i, int isf) {
  return isf ? ((const float*)p)[i] : b2f(((const u16*)p)[i]);
}

typedef __attribute__((ext_vector_type(8))) short bf16x8;  // 8 bf16 = 4 VGPRs
typedef __attribute__((ext_vector_type(4))) float f32x4;

__device__ __forceinline__ void gld_lds16(const u16* g, u16* l) {
  __builtin_amdgcn_global_load_lds((const __attribute__((address_space(1))) void*)g,
                                   (__attribute__((address_space(3))) void*)l, 16, 0, 0);
}

// ---------- runtime dtype detection (1 = f32 inputs, 0 = bf16 inputs) ----------
__global__ void detect_dtype(const u16* __restrict__ x, int* flag) {
  __shared__ int cnt;
  if (threadIdx.x == 0) cnt = 0;
  __syncthreads();
  int c = 0;
  for (int i = threadIdx.x; i < 4096; i += 256) {
    u16 u = x[2 * i];
    int e = (u >> 7) & 0xFF;
    if (e >= 118 && e <= 135) c++;
  }
  atomicAdd(&cnt, c);
  __syncthreads();
  if (threadIdx.x == 0) *flag = (cnt > 2048) ? 0 : 1;
}

// ---------- generic convert-to-bf16 (grid-stride) ----------
__global__ void conv_any(const void* __restrict__ src, u16* __restrict__ dst,
                         long n, const int* __restrict__ flag) {
  long i = (long)blockIdx.x * 256 + threadIdx.x;
  long stride = (long)gridDim.x * 256;
  int isf = *flag;
  if (isf) {
    const float* s = (const float*)src;
    for (long j = i; j < n; j += stride) dst[j] = f2b(s[j]);
  } else {
    const u16* s = (const u16*)src;
    for (long j = i; j < n; j += stride) dst[j] = s[j];
  }
}

// ---------- fused small conversions: one block per tensor ----------
#define NSMALL 13
struct SmallConv {
  const void* src[NSMALL];
  u16*        dst[NSMALL];
  int         n[NSMALL];
};
__global__ void conv_small(SmallConv sc, const int* __restrict__ flag) {
  int b = blockIdx.x;
  int isf = *flag;
  const void* s = sc.src[b];
  u16* d = sc.dst[b];
  int n = sc.n[b];
  if (isf) {
    const float* sf = (const float*)s;
    for (int i = threadIdx.x; i < n; i += 256) d[i] = f2b(sf[i]);
  } else {
    const u16* sb = (const u16*)s;
    for (int i = threadIdx.x; i < n; i += 256) d[i] = sb[i];
  }
}

// ---------- weight packing: transpose [K,Ncols] (f32 or bf16) -> dst[Ncols,K] bf16 ----------
__global__ __launch_bounds__(256) void transpose_any(const void* __restrict__ src,
                                                     u16* __restrict__ dst,
                                                     int K, int Ncols,
                                                     const int* __restrict__ flag) {
  __shared__ u16 tile[32][33];
  int isf = *flag;
  int tx = threadIdx.x & 31, ty = threadIdx.x >> 5;   // 32 x 8
  int c0 = blockIdx.x * 32, r0 = blockIdx.y * 32;
  if (isf) {
    const float* s = (const float*)src;
    #pragma unroll
    for (int i = 0; i < 32; i += 8)
      tile[ty + i][tx] = f2b(s[(long)(r0 + ty + i) * Ncols + c0 + tx]);
  } else {
    const u16* s = (const u16*)src;
    #pragma unroll
    for (int i = 0; i < 32; i += 8)
      tile[ty + i][tx] = s[(long)(r0 + ty + i) * Ncols + c0 + tx];
  }
  __syncthreads();
  #pragma unroll
  for (int i = 0; i < 32; i += 8)
    dst[(long)(c0 + ty + i) * K + r0 + tx] = tile[tx][ty + i];
}

// bias1 layout: [0:4096)=bq1 [4096:8192)=bk1 [8192:12288)=bv1 [12288:16384)=bs1 [16384:20480)=0
__global__ void pack_bias(const void* bq1, const void* bk1, const void* bv1, const void* bs1,
                          const void* bq2, const void* bk2, const void* bv2, const void* bs2,
                          float* bias1, float* bias2, const int* flag) {
  int isf = *flag;
  int i = blockIdx.x * 256 + threadIdx.x;
  if (i < 20480) {
    float v = 0.f;
    if (i < 4096) v = ldf(bq1, i, isf);
    else if (i < 8192)  v = ldf(bk1, i - 4096, isf);
    else if (i < 12288) v = ldf(bv1, i - 8192, isf);
    else if (i < 16384) v = ldf(bs1, i - 12288, isf);
    bias1[i] = v;
  } else if (i < 20480 + N2) {
    int j = i - 20480; float v = 0.f;
    if (j < 64) v = ldf(bq2, j, isf);
    else if (j < 128) v = ldf(bk2, j - 64, isf);
    else if (j < 192) v = ldf(bv2, j - 128, isf);
    else if (j < 256) v = ldf(bs2, j - 192, isf);
    bias2[j] = v;
  }
}

// ---------- GEMM 128x128 tile, 3-deep LDS ring, counted vmcnt pipeline (VERIFIED R2) ----------
// C = A[M,K] * BT[N,K]^T + bias.  K multiple of 32, K/32 >= 2.
// DEFAULT block order: gridDim.x=64 -> round-robin pins bx%8 per XCD -> B-panels L2-resident.
// LDS col-group XOR-swizzle (0 bank conflicts): phys_cg = logical_cg ^ ((row>>1)&3)
// Per K-tile t: s_waitcnt vmcnt(4); s_barrier; STAGE(t+2); ds_read frags(buf t%3); 16 MFMA.
__global__ __launch_bounds__(256) void gemm_bt_r3(const u16* __restrict__ A,
                                                  const u16* __restrict__ BT,
                                                  const float* __restrict__ bias,
                                                  u16* __restrict__ C,
                                                  int M, int N, int K) {
  __shared__ u16 As[3][128 * 32];   // 3 x 8 KB
  __shared__ u16 Bs[3][128 * 32];   // 3 x 8 KB  (total 48 KB -> 3 blocks/CU)

  const int tid = threadIdx.x, lane = tid & 63, wave = tid >> 6;
  const int m0 = blockIdx.y * 128, n0 = blockIdx.x * 128;
  const int wm = (wave >> 1) * 64, wn = (wave & 1) * 64;

  const int srow = tid >> 2, scp = tid & 3;
  const int scl8 = (scp ^ ((srow >> 1) & 3)) * 8;   // swizzled logical col-group
  int ar0 = m0 + srow;      if (ar0 >= M) ar0 = M - 1;
  int ar1 = m0 + srow + 64; if (ar1 >= M) ar1 = M - 1;
  const u16* ag0 = A + (long)ar0 * K + scl8;
  const u16* ag1 = A + (long)ar1 * K + scl8;
  const u16* bg0 = BT + (long)(n0 + srow) * K + scl8;
  const u16* bg1 = BT + (long)(n0 + srow + 64) * K + scl8;

  f32x4 acc[4][4];
  #pragma unroll
  for (int i = 0; i < 4; i++)
    #pragma unroll
    for (int j = 0; j < 4; j++) { f32x4 z = {0.f, 0.f, 0.f, 0.f}; acc[i][j] = z; }

  const int fr = lane & 15, q = lane >> 4;
  const int fq = (q ^ ((fr >> 1) & 3)) * 8;         // matching swizzle on read
  const int aoff = (wm + fr) * 32 + fq;
  const int boff = (wn + fr) * 32 + fq;

  const int NT = K >> 5;

  auto STAGE = [&](int t, int b) {
    const long k0 = (long)t * 32;
    gld_lds16(ag0 + k0, &As[b][(size_t)tid * 8]);
    gld_lds16(ag1 + k0, &As[b][2048 + (size_t)tid * 8]);
    gld_lds16(bg0 + k0, &Bs[b][(size_t)tid * 8]);
    gld_lds16(bg1 + k0, &Bs[b][2048 + (size_t)tid * 8]);
  };

  STAGE(0, 0); STAGE(1, 1);

  int cur = 0, nxt = 2;
  for (int t = 0; t < NT; ++t) {
    if (t < NT - 1) {
      asm volatile("s_waitcnt vmcnt(4)\n\ts_barrier" ::: "memory");
    } else {
      asm volatile("s_waitcnt vmcnt(0)\n\ts_barrier" ::: "memory");
    }
    if (t + 2 < NT) STAGE(t + 2, nxt);

    const u16* ab = &As[cur][0];
    const u16* bb = &Bs[cur][0];
    bf16x8 af[4], bfv[4];
    #pragma unroll
    for (int i = 0; i < 4; i++) af[i]  = *(const bf16x8*)(ab + aoff + i * 512);
    #pragma unroll
    for (int j = 0; j < 4; j++) bfv[j] = *(const bf16x8*)(bb + boff + j * 512);

    #pragma unroll
    for (int i = 0; i < 4; i++)
      #pragma unroll
      for (int j = 0; j < 4; j++)
        acc[i][j] = __builtin_amdgcn_mfma_f32_16x16x32_bf16(af[i], bfv[j], acc[i][j], 0, 0, 0);

    cur = (cur == 2) ? 0 : cur + 1;
    nxt = (nxt == 2) ? 0 : nxt + 1;
  }

  const int q4 = (lane >> 4) * 4, cl = lane & 15;
  #pragma unroll
  for (int i = 0; i < 4; i++)
    #pragma unroll
    for (int r = 0; r < 4; r++) {
      int row = m0 + wm + i * 16 + q4 + r;
      if (row < M) {
        #pragma unroll
        for (int j = 0; j < 4; j++) {
          int col = n0 + wn + j * 16 + cl;
          C[(long)row * N + col] = f2b(acc[i][j][r] + bias[col]);
        }
      }
    }
}

// ---------- merged layer-2 GEMM: 5 n-tiles of 64, M=6720, K=4096, BK=64 ----------
// nt<4: A=h1 (t2 q|k|v|skip); nt==4: A=z1 (g2). Swizzle: phys_cg = logical ^ (row&7).
// NEW: nt==4 epilogue also computes es2/ed2 (GAT2 dots) from the bit-exact y2 values
// (f2b/b2f round-trip matches what g2_dots would have read back).
__global__ __launch_bounds__(256) void gemm2_64(const u16* __restrict__ h1,
                                                const u16* __restrict__ z1,
                                                const u16* __restrict__ wt2,
                                                const float* __restrict__ bias2,
                                                const u16* __restrict__ as64,
                                                const u16* __restrict__ ad64,
                                                u16* __restrict__ y2,
                                                float* __restrict__ es2,
                                                float* __restrict__ ed2) {
  __shared__ u16 As[64 * 64];
  __shared__ u16 Bs[64 * 64];
  const int nt = blockIdx.x;
  const u16* A = (nt < 4) ? h1 : z1;
  const u16* BT = wt2 + (size_t)nt * 64 * D1;
  const int m0 = blockIdx.y * 64, n0 = nt * 64;
  const int tid = threadIdx.x, lane = tid & 63, wave = tid >> 6;

  const int sr = tid >> 3, cp = tid & 7;
  const int cgl8 = (cp ^ (sr & 7)) * 8;
  const u16* ag0 = A + (long)(m0 + sr) * D1 + cgl8;
  const u16* ag1 = ag0 + (long)32 * D1;
  const u16* bg0 = BT + (long)sr * D1 + cgl8;
  const u16* bg1 = bg0 + (long)32 * D1;
  u16* al0 = As + tid * 8;  u16* al1 = As + 2048 + tid * 8;
  u16* bl0 = Bs + tid * 8;  u16* bl1 = Bs + 2048 + tid * 8;

  f32x4 acc[4];
  #pragma unroll
  for (int j = 0; j < 4; j++) { f32x4 z = {0.f, 0.f, 0.f, 0.f}; acc[j] = z; }

  const int fr = lane & 15, q = lane >> 4;
  const int x0 = ((q)     ^ (fr & 7)) * 8;
  const int x1 = ((4 + q) ^ (fr & 7)) * 8;
  const u16* apA = As + (wave * 16 + fr) * 64;

  for (int k0 = 0; k0 < D1; k0 += 64) {
    __syncthreads();
    gld_lds16(ag0 + k0, al0);
    gld_lds16(ag1 + k0, al1);
    gld_lds16(bg0 + k0, bl0);
    gld_lds16(bg1 + k0, bl1);
    __syncthreads();
    bf16x8 a0 = *(const bf16x8*)(apA + x0);
    bf16x8 a1 = *(const bf16x8*)(apA + x1);
    #pragma unroll
    for (int j = 0; j < 4; j++) {
      bf16x8 b0 = *(const bf16x8*)(Bs + (j * 16 + fr) * 64 + x0);
      acc[j] = __builtin_amdgcn_mfma_f32_16x16x32_bf16(a0, b0, acc[j], 0, 0, 0);
    }
    #pragma unroll
    for (int j = 0; j < 4; j++) {
      bf16x8 b1 = *(const bf16x8*)(Bs + (j * 16 + fr) * 64 + x1);
      acc[j] = __builtin_amdgcn_mfma_f32_16x16x32_bf16(a1, b1, acc[j], 0, 0, 0);
    }
  }
  const int q4 = (lane >> 4) * 4, cl = lane & 15;
  #pragma unroll
  for (int j = 0; j < 4; j++)
    #pragma unroll
    for (int r = 0; r < 4; r++) {
      int row = m0 + wave * 16 + q4 + r;
      int col = n0 + j * 16 + cl;
      y2[(long)row * N2 + col] = f2b(acc[j][r] + bias2[col]);
    }
  if (nt == 4) {
    // es2/ed2: per-row dot of (rounded) gat slice with a_src/a_dst
    #pragma unroll
    for (int r = 0; r < 4; r++) {
      int row = m0 + wave * 16 + q4 + r;
      float s1 = 0.f, s2 = 0.f;
      #pragma unroll
      for (int j = 0; j < 4; j++) {
        int col = j * 16 + cl;
        float v = b2f(f2b(acc[j][r] + bias2[256 + col]));
        s1 += v * b2f(as64[col]);
        s2 += v * b2f(ad64[col]);
      }
      #pragma unroll
      for (int o = 1; o < 16; o <<= 1) {
        s1 += __shfl_xor(s1, o, 64);
        s2 += __shfl_xor(s2, o, 64);
      }
      if (cl == 0) { es2[row] = s1; ed2[row] = s2; }
    }
  }
}

// ---------- CSR build ----------
__global__ void zero_kernel(int* deg, float* f1sum) {
  int i = blockIdx.x * 256 + threadIdx.x;
  if (i < NNODES) deg[i] = 0;
  if (i < NGRAPH * 256) f1sum[i] = 0.f;
}

__global__ void count_deg(const int* __restrict__ ei, int* deg) {
  int e = blockIdx.x * 256 + threadIdx.x;
  if (e < NEDGES) atomicAdd(&deg[ei[NEDGES + e]], 1);
}

__global__ __launch_bounds__(1024) void scan_deg(const int* __restrict__ deg, int* off, int* cur) {
  __shared__ int sh[1024];
  const int t = threadIdx.x;
  const int PER = 7;
  int base = t * PER;
  int loc[PER];
  int sum = 0;
  #pragma unroll
  for (int i = 0; i < PER; i++) {
    int v = (base + i < NNODES) ? deg[base + i] : 0;
    loc[i] = sum; sum += v;
  }
  sh[t] = sum;
  __syncthreads();
  for (int d = 1; d < 1024; d <<= 1) {
    int v = (t >= d) ? sh[t - d] : 0;
    __syncthreads();
    sh[t] += v;
    __syncthreads();
  }
  int prev = (t > 0) ? sh[t - 1] : 0;
  #pragma unroll
  for (int i = 0; i < PER; i++) {
    int idx = base + i;
    if (idx <= NNODES) {
      int v = prev + loc[i];
      off[idx] = v;
      if (idx < NNODES) cur[idx] = v;
    }
  }
}

__global__ void scatter_edges(const int* __restrict__ ei, int* cur,
                              int* esrc, int* edst) {
  int e = blockIdx.x * 256 + threadIdx.x;
  if (e < NEDGES) {
    int s = ei[e], d = ei[NEDGES + e];
    int p = atomicAdd(&cur[d], 1);
    esrc[p] = s; edst[p] = d;
  }
}

// ---------- T1 fused scores + segment softmax (block per dst node) ----------
__global__ __launch_bounds__(256) void t1_score_sm(const u16* __restrict__ yqk,
                                                   const int* __restrict__ off,
                                                   const int* __restrict__ esrc,
                                                   float* __restrict__ sc) {
  __shared__ float qsh[4096];
  __shared__ float sm[SMCAP * 4];
  int n = blockIdx.x, tid = threadIdx.x, lane = tid & 63, wave = tid >> 6;
  const u16* qr = yqk + (long)n * 8192;
  for (int i = tid * 8; i < 4096; i += 2048) {
    uint4 qa = *(const uint4*)(qr + i);
    const u16* qs = (const u16*)&qa;
    #pragma unroll
    for (int j = 0; j < 8; j++) qsh[i + j] = b2f(qs[j]);
  }
  __syncthreads();
  int p0 = off[n], p1 = off[n + 1], deg = p1 - p0;
  bool fits = (deg <= SMCAP);
  for (int p = p0 + wave; p < p1; p += 4) {
    const u16* k = yqk + (long)esrc[p] * 8192 + 4096;
    float dot[HEADS1];
    #pragma unroll
    for (int h = 0; h < HEADS1; h++) dot[h] = 0.f;
    #pragma unroll
    for (int h = 0; h < HEADS1; h++) {
      #pragma unroll
      for (int c = 0; c < 2; c++) {
        int idx = h * C1DIM + c * 512 + lane * 8;
        uint4 ka = *(const uint4*)(k + idx);
        const u16* ks = (const u16*)&ka;
        #pragma unroll
        for (int i = 0; i < 8; i++) dot[h] += qsh[idx + i] * b2f(ks[i]);
      }
    }
    #pragma unroll
    for (int h = 0; h < HEADS1; h++) {
      float v = dot[h];
      #pragma unroll
      for (int o = 32; o > 0; o >>= 1) v += __shfl_xor(v, o, 64);
      if (lane == 0) {
        float sv = v * (1.0f / 32.0f);
        if (fits) sm[(p - p0) * 4 + h] = sv;
        else      sc[(long)p * HEADS1 + h] = sv;
      }
    }
  }
  __syncthreads();
  if (fits) {
    int h = wave;   // 4 waves = 4 heads
    float m = -3.4e38f;
    for (int e = lane; e < deg; e += 64) m = fmaxf(m, sm[e * 4 + h]);
    #pragma unroll
    for (int o = 32; o > 0; o >>= 1) m = fmaxf(m, __shfl_xor(m, o, 64));
    float s = 0.f;
    for (int e = lane; e < deg; e += 64) {
      float ex = __expf(sm[e * 4 + h] - m);
      sm[e * 4 + h] = ex; s += ex;
    }
    #pragma unroll
    for (int o = 32; o > 0; o >>= 1) s += __shfl_xor(s, o, 64);
    float inv = 1.0f / (s + 1e-16f);
    for (int e = lane; e < deg; e += 64)
      sc[(long)(p0 + e) * 4 + h] = sm[e * 4 + h] * inv;
  } else if (tid < 4) {
    int h = tid;
    float m = -3.4e38f;
    for (int p = p0; p < p1; p++) m = fmaxf(m, sc[(long)p * 4 + h]);
    float s = 0.f;
    for (int p = p0; p < p1; p++) {
      float ex = __expf(sc[(long)p * 4 + h] - m);
      sc[(long)p * 4 + h] = ex; s += ex;
    }
    float inv = 1.0f / (s + 1e-16f);
    for (int p = p0; p < p1; p++) sc[(long)p * 4 + h] *= inv;
  }
}

// ---------- T1 aggregate: yvs rows [v(4096) | skip(4096)], stride 8192 ----------
__global__ __launch_bounds__(256) void t1_agg(const u16* __restrict__ yvs,
                                              const int* __restrict__ off,
                                              const int* __restrict__ esrc,
                                              const float* __restrict__ alpha,
                                              u16* __restrict__ h1) {
  int n = blockIdx.x, t = threadIdx.x, h = t >> 6;
  int p0 = off[n], p1 = off[n + 1];
  float acc[16];
  #pragma unroll
  for (int i = 0; i < 16; i++) acc[i] = 0.f;
  for (int p = p0; p < p1; p++) {
    float a = alpha[p * 4 + h];
    const u16* v = yvs + (long)esrc[p] * 8192 + t * 16;
    uint4 v0 = *(const uint4*)(v);
    uint4 v1 = *(const uint4*)(v + 8);
    const u16* s0 = (const u16*)&v0; const u16* s1 = (const u16*)&v1;
    #pragma unroll
    for (int i = 0; i < 8; i++) acc[i] += a * b2f(s0[i]);
    #pragma unroll
    for (int i = 0; i < 8; i++) acc[8 + i] += a * b2f(s1[i]);
  }
  const u16* sk = yvs + (long)n * 8192 + 4096 + t * 16;
  uint4 k0 = *(const uint4*)(sk); uint4 k1 = *(const uint4*)(sk + 8);
  const u16* ks0 = (const u16*)&k0; const u16* ks1 = (const u16*)&k1;
  u16 outv[16];
  #pragma unroll
  for (int i = 0; i < 8; i++) outv[i] = f2b(fmaxf(acc[i] + b2f(ks0[i]), 0.f));
  #pragma unroll
  for (int i = 0; i < 8; i++) outv[8 + i] = f2b(fmaxf(acc[8 + i] + b2f(ks1[i]), 0.f));
  *(uint4*)(h1 + (long)n * D1 + t * 16) = *(uint4*)outv;
  *(uint4*)(h1 + (long)n * D1 + t * 16 + 8) = *(uint4*)(outv + 8);
}

// ---------- GAT1: per-node attention dots (gat compact [N,4096]) ----------
__global__ __launch_bounds__(256) void g1_dots(const u16* __restrict__ gat,
                                               const u16* __restrict__ a_src,
                                               const u16* __restrict__ a_dst,
                                               float* __restrict__ es, float* __restrict__ ed) {
  int n = blockIdx.x;
  int h = threadIdx.x >> 6, lane = threadIdx.x & 63;
  const u16* hr = gat + (long)n * D1 + h * C1DIM;
  const u16* as = a_src + h * C1DIM;
  const u16* ad = a_dst + h * C1DIM;
  float s1 = 0.f, s2 = 0.f;
  #pragma unroll
  for (int c = 0; c < 2; c++) {
    int idx = c * 512 + lane * 8;
    uint4 hv = *(const uint4*)(hr + idx);
    uint4 av = *(const uint4*)(as + idx);
    uint4 dv = *(const uint4*)(ad + idx);
    const u16* hs = (const u16*)&hv; const u16* a1 = (const u16*)&av; const u16* d1 = (const u16*)&dv;
    #pragma unroll
    for (int i = 0; i < 8; i++) {
      float x = b2f(hs[i]);
      s1 += x * b2f(a1[i]); s2 += x * b2f(d1[i]);
    }
  }
  #pragma unroll
  for (int o = 32; o > 0; o >>= 1) { s1 += __shfl_xor(s1, o, 64); s2 += __shfl_xor(s2, o, 64); }
  if (lane == 0) { es[n * 4 + h] = s1; ed[n * 4 + h] = s2; }
}

// ---------- GAT1 fused scores (leaky 0.2) + segment softmax with self loop ----------
__global__ __launch_bounds__(256) void g1_score_sm(const int* __restrict__ off,
                                                   const int* __restrict__ esrc,
                                                   const float* __restrict__ es,
                                                   const float* __restrict__ ed,
                                                   float* __restrict__ sc,
                                                   float* __restrict__ selfsc) {
  __shared__ float sm[SMCAP * 4];
  int n = blockIdx.x, tid = threadIdx.x, lane = tid & 63, wave = tid >> 6;
  int p0 = off[n], p1 = off[n + 1], deg = p1 - p0;
  bool fits = (deg <= SMCAP);
  for (int idx = tid; idx < deg * 4; idx += 256) {
    int e = idx >> 2, h = idx & 3;
    float v = es[esrc[p0 + e] * 4 + h] + ed[n * 4 + h];
    v = (v > 0.f) ? v : 0.2f * v;
    if (fits) sm[idx] = v;
    else      sc[(long)(p0 + e) * 4 + h] = v;
  }
  __syncthreads();
  if (fits) {
    int h = wave;
    float sv = es[n * 4 + h] + ed[n * 4 + h];
    sv = (sv > 0.f) ? sv : 0.2f * sv;
    float m = sv;
    for (int e = lane; e < deg; e += 64) m = fmaxf(m, sm[e * 4 + h]);
    #pragma unroll
    for (int o = 32; o > 0; o >>= 1) m = fmaxf(m, __shfl_xor(m, o, 64));
    float s = 0.f;
    for (int e = lane; e < deg; e += 64) {
      float ex = __expf(sm[e * 4 + h] - m);
      sm[e * 4 + h] = ex; s += ex;
    }
    #pragma unroll
    for (int o = 32; o > 0; o >>= 1) s += __shfl_xor(s, o, 64);
    float selfe = __expf(sv - m);
    float inv = 1.0f / (s + selfe + 1e-16f);
    for (int e = lane; e < deg; e += 64)
      sc[(long)(p0 + e) * 4 + h] = sm[e * 4 + h] * inv;
    if (lane == 0) selfsc[n * 4 + h] = selfe * inv;
  } else if (tid < 4) {
    int h = tid;
    float sv = es[n * 4 + h] + ed[n * 4 + h];
    sv = (sv > 0.f) ? sv : 0.2f * sv;
    float m = sv;
    for (int p = p0; p < p1; p++) m = fmaxf(m, sc[(long)p * 4 + h]);
    float s = 0.f;
    for (int p = p0; p < p1; p++) {
      float ex = __expf(sc[(long)p * 4 + h] - m);
      sc[(long)p * 4 + h] = ex; s += ex;
    }
    float selfe = __expf(sv - m);
    float inv = 1.0f / (s + selfe + 1e-16f);
    for (int p = p0; p < p1; p++) sc[(long)p * 4 + h] *= inv;
    selfsc[n * 4 + h] = selfe * inv;
  }
}

// ---------- GAT1 aggregate (gat compact [N,4096]) -> z1 ----------
__global__ __launch_bounds__(256) void g1_agg(const u16* __restrict__ gat,
                                              const int* __restrict__ off,
                                              const int* __restrict__ esrc,
                                              const float* __restrict__ alpha,
                                              const float* __restrict__ selfa,
                                              const u16* __restrict__ bias,
                                              u16* __restrict__ z1) {
  int n = blockIdx.x, t = threadIdx.x, h = t >> 6;
  int p0 = off[n], p1 = off[n + 1];
  float acc[16];
  #pragma unroll
  for (int i = 0; i < 16; i++) acc[i] = 0.f;
  for (int p = p0; p < p1; p++) {
    float a = alpha[p * 4 + h];
    const u16* v = gat + (long)esrc[p] * D1 + t * 16;
    uint4 v0 = *(const uint4*)(v);
    uint4 v1 = *(const uint4*)(v + 8);
    const u16* s0 = (const u16*)&v0; const u16* s1 = (const u16*)&v1;
    #pragma unroll
    for (int i = 0; i < 8; i++) acc[i] += a * b2f(s0[i]);
    #pragma unroll
    for (int i = 0; i < 8; i++) acc[8 + i] += a * b2f(s1[i]);
  }
  {
    float a = selfa[n * 4 + h];
    const u16* v = gat + (long)n * D1 + t * 16;
    uint4 v0 = *(const uint4*)(v);
    uint4 v1 = *(const uint4*)(v + 8);
    const u16* s0 = (const u16*)&v0; const u16* s1 = (const u16*)&v1;
    #pragma unroll
    for (int i = 0; i < 8; i++) acc[i] += a * b2f(s0[i]);
    #pragma unroll
    for (int i = 0; i < 8; i++) acc[8 + i] += a * b2f(s1[i]);
  }
  u16 outv[16];
  #pragma unroll
  for (int i = 0; i < 16; i++) outv[i] = f2b(fmaxf(acc[i] + b2f(bias[t * 16 + i]), 0.f));
  *(uint4*)(z1 + (long)n * D1 + t * 16) = *(uint4*)outv;
  *(uint4*)(z1 + (long)n * D1 + t * 16 + 8) = *(uint4*)(outv + 8);
}

// ---------- fused layer-2 scores + softmax (T2 dot + G2 gat), block per dst node ----------
__global__ __launch_bounds__(256) void t2g2_score_sm(const u16* __restrict__ y2,
                                                     const int* __restrict__ off,
                                                     const int* __restrict__ esrc,
                                                     const float* __restrict__ es2,
                                                     const float* __restrict__ ed2,
                                                     float* __restrict__ scT,
                                                     float* __restrict__ scG,
                                                     float* __restrict__ sfG) {
  __shared__ float smT[SMCAP];
  __shared__ float smG[SMCAP];
  int n = blockIdx.x, tid = threadIdx.x, lane = tid & 63, wave = tid >> 6;
  int p0 = off[n], p1 = off[n + 1], deg = p1 - p0;
  bool fits = (deg <= SMCAP);
  float qv = b2f(y2[(long)n * N2 + lane]);
  float edn = ed2[n];
  for (int e = wave; e < deg; e += 4) {
    int s = esrc[p0 + e];
    float kv = b2f(y2[(long)s * N2 + C2DIM + lane]);
    float d = qv * kv;
    #pragma unroll
    for (int o = 32; o > 0; o >>= 1) d += __shfl_xor(d, o, 64);
    if (lane == 0) {
      float vt = d * 0.125f;
      float vg = es2[s] + edn;
      vg = (vg > 0.f) ? vg : 0.2f * vg;
      if (fits) { smT[e] = vt; smG[e] = vg; }
      else      { scT[p0 + e] = vt; scG[p0 + e] = vg; }
    }
  }
  __syncthreads();
  if (fits) {
    if (wave == 0) {       // T2 softmax (no self)
      float m = -3.4e38f;
      for (int e = lane; e < deg; e += 64) m = fmaxf(m, smT[e]);
      #pragma unroll
      for (int o = 32; o > 0; o >>= 1) m = fmaxf(m, __shfl_xor(m, o, 64));
      float s = 0.f;
      for (int e = lane; e < deg; e += 64) { float ex = __expf(smT[e] - m); smT[e] = ex; s += ex; }
      #pragma unroll
      for (int o = 32; o > 0; o >>= 1) s += __shfl_xor(s, o, 64);
      float inv = 1.0f / (s + 1e-16f);
      for (int e = lane; e < deg; e += 64) scT[p0 + e] = smT[e] * inv;
    } else if (wave == 1) { // G2 softmax (with self)
      float sv = es2[n] + edn;
      sv = (sv > 0.f) ? sv : 0.2f * sv;
      float m = sv;
      for (int e = lane; e < deg; e += 64) m = fmaxf(m, smG[e]);
      #pragma unroll
      for (int o = 32; o > 0; o >>= 1) m = fmaxf(m, __shfl_xor(m, o, 64));
      float s = 0.f;
      for (int e = lane; e < deg; e += 64) { float ex = __expf(smG[e] - m); smG[e] = ex; s += ex; }
      #pragma unroll
      for (int o = 32; o > 0; o >>= 1) s += __shfl_xor(s, o, 64);
      float selfe = __expf(sv - m);
      float inv = 1.0f / (s + selfe + 1e-16f);
      for (int e = lane; e < deg; e += 64) scG[p0 + e] = smG[e] * inv;
      if (lane == 0) sfG[n] = selfe * inv;
    }
  } else {
    if (tid == 0) {
      float m = -3.4e38f;
      for (int p = p0; p < p1; p++) m = fmaxf(m, scT[p]);
      float s = 0.f;
      for (int p = p0; p < p1; p++) { float ex = __expf(scT[p] - m); scT[p] = ex; s += ex; }
      float inv = 1.0f / (s + 1e-16f);
      for (int p = p0; p < p1; p++) scT[p] *= inv;
    } else if (tid == 1) {
      float sv = es2[n] + edn;
      sv = (sv > 0.f) ? sv : 0.2f * sv;
      float m = sv;
      for (int p = p0; p < p1; p++) m = fmaxf(m, scG[p]);
      float s = 0.f;
      for (int p = p0; p < p1; p++) { float ex = __expf(scG[p] - m); scG[p] = ex; s += ex; }
      float selfe = __expf(sv - m);
      float inv = 1.0f / (s + selfe + 1e-16f);
      for (int p = p0; p < p1; p++) scG[p] *= inv;
      sfG[n] = selfe * inv;
    }
  }
}

// ---------- merged layer-2 aggregate: sn = relu(T2) + relu(G2), wave per node ----------
__global__ __launch_bounds__(256) void tg2_agg(const u16* __restrict__ y2,
                                               const int* __restrict__ off,
                                               const int* __restrict__ esrc,
                                               const float* __restrict__ alphaT,
                                               const float* __restrict__ alphaG,
                                               const float* __restrict__ selfaG,
                                               const u16* __restrict__ bias,
                                               float* __restrict__ sn) {
  int n = (blockIdx.x * 256 + threadIdx.x) >> 6, lane = threadIdx.x & 63;
  if (n >= NNODES) return;
  int p0 = off[n], p1 = off[n + 1];
  float at = 0.f, ag = 0.f;
  for (int p = p0; p < p1; p++) {
    const u16* row = y2 + (long)esrc[p] * N2;
    at += alphaT[p] * b2f(row[2 * C2DIM + lane]);
    ag += alphaG[p] * b2f(row[4 * C2DIM + lane]);
  }
  at += b2f(y2[(long)n * N2 + 3 * C2DIM + lane]);                 // T2 skip
  ag += selfaG[n] * b2f(y2[(long)n * N2 + 4 * C2DIM + lane]);     // G2 self
  sn[(long)n * C2DIM + lane] = fmaxf(at, 0.f) + fmaxf(ag + b2f(bias[lane]), 0.f);
}

// ---------- MLP head ----------
#define FCHUNK 210   // 26880 = 128 * 210
__global__ __launch_bounds__(256) void fc1_partial(const float* __restrict__ sn,
                                                   const void* __restrict__ w,
                                                   const int* __restrict__ flag,
                                                   float* __restrict__ f1sum) {
  __shared__ float sl[16 * FCHUNK];
  int k0 = blockIdx.x * FCHUNK;
  int t = threadIdx.x;
  int isf = *flag;
  for (int idx = t; idx < 16 * FCHUNK; idx += 256) {
    int g = idx / FCHUNK, kk = idx - g * FCHUNK;
    sl[idx] = sn[(long)g * 26880 + k0 + kk];
  }
  __syncthreads();
  float acc[16];
  #pragma unroll
  for (int g = 0; g < 16; g++) acc[g] = 0.f;
  if (isf) {
    const float* wf = (const float*)w;
    for (int kk = 0; kk < FCHUNK; kk++) {
      float wv = wf[(long)(k0 + kk) * 256 + t];
      #pragma unroll
      for (int g = 0; g < 16; g++) acc[g] += sl[g * FCHUNK + kk] * wv;
    }
  } else {
    const u16* wb = (const u16*)w;
    for (int kk = 0; kk < FCHUNK; kk++) {
      float wv = b2f(wb[(long)(k0 + kk) * 256 + t]);
      #pragma unroll
      for (int g = 0; g < 16; g++) acc[g] += sl[g * FCHUNK + kk] * wv;
    }
  }
  #pragma unroll
  for (int g = 0; g < 16; g++) atomicAdd(&f1sum[g * 256 + t], acc[g]);
}

__global__ __launch_bounds__(256) void fc_tail(const float* __restrict__ f1sum,
                                               const u16* b1, const u16* w2, const u16* b2,
                                               const u16* w3, const u16* b3,
                                               const u16* w4, const u16* b4,
                                               void* __restrict__ out,
                                               const int* __restrict__ flag) {
  __shared__ float A1[16 * 256];
  __shared__ float A2[16 * 128];
  __shared__ float A3[16 * 64];
  int isf = *flag;
  int t = threadIdx.x;
  for (int i = t; i < 4096; i += 256) A1[i] = fmaxf(f1sum[i] + b2f(b1[i & 255]), 0.f);
  __syncthreads();
  for (int i = t; i < 2048; i += 256) {
    int g = i >> 7, j = i & 127;
    float acc = b2f(b2[j]);
    for (int k = 0; k < 256; k++) acc += A1[g * 256 + k] * b2f(w2[k * 128 + j]);
    A2[i] = fmaxf(acc, 0.f);
  }
  __syncthreads();
  for (int i = t; i < 1024; i += 256) {
    int g = i >> 6, j = i & 63;
    float acc = b2f(b3[j]);
    for (int k = 0; k < 128; k++) acc += A2[g * 128 + k] * b2f(w3[k * 64 + j]);
    A3[i] = fmaxf(acc, 0.f);
  }
  __syncthreads();
  for (int i = t; i < NGRAPH * OUTDIM; i += 256) {
    int g = i / OUTDIM, j = i - g * OUTDIM;
    float acc = b2f(b4[j]);
    for (int k = 0; k < 64; k++) acc += A3[g * 64 + k] * b2f(w4[k * OUTDIM + j]);
    if (isf) ((float*)out)[i] = acc;
    else     ((u16*)out)[i] = f2b(acc);
  }
}

// ---------- host ----------
extern "C" void kernel_launch(void* const* d_in, const int* in_sizes, int n_in,
                              void* d_out, int out_size, void* d_ws, size_t ws_size,
                              hipStream_t stream) {
  const void* x     = d_in[0];
  const int*  ei    = (const int*)d_in[1];
  const void* t1_wq = d_in[2];
  const void* t1_wk = d_in[3];
  const void* t1_wv = d_in[4];
  const void* t1_ws = d_in[5];
  const void* t1_bq = d_in[6];
  const void* t1_bk = d_in[7];
  const void* t1_bv = d_in[8];
  const void* t1_bs = d_in[9];
  const void* t2_wq = d_in[10];
  const void* t2_wk = d_in[11];
  const void* t2_wv = d_in[12];
  const void* t2_ws = d_in[13];
  const void* t2_bq = d_in[14];
  const void* t2_bk = d_in[15];
  const void* t2_bv = d_in[16];
  const void* t2_bs = d_in[17];
  const void* g1_w  = d_in[18];
  const void* g1_as = d_in[19];
  const void* g1_ad = d_in[20];
  const void* g1_b  = d_in[21];
  const void* g2_w  = d_in[22];
  const void* g2_as = d_in[23];
  const void* g2_ad = d_in[24];
  const void* g2_b  = d_in[25];
  const void* fc1_w = d_in[26];
  const void* fc1_b = d_in[27];
  const void* fc2_w = d_in[28];
  const void* fc2_b = d_in[29];
  const void* fc3_w = d_in[30];
  const void* fc3_b = d_in[31];
  const void* fc4_w = d_in[32];
  const void* fc4_b = d_in[33];

  char* wp = (char*)d_ws;
  auto alloc = [&](size_t bytes) {
    char* p = wp; wp += (bytes + 255) & ~(size_t)255; return p;
  };
  u16*   wtSlab = (u16*)  alloc((size_t)8192 * INDIM * 2);       // 33.6 MB, reused per phase
  u16*   wt2    = (u16*)  alloc((size_t)N2 * D1 * 2);            // 2.6 MB
  u16*   yqk    = (u16*)  alloc((size_t)NNODES * 8192 * 2);      // 110 MB, phased
  u16*   h1     = (u16*)  alloc((size_t)NNODES * D1 * 2);        // 55 MB
  u16*   y2     = (u16*)  alloc((size_t)NNODES * N2 * 2);        // 4.3 MB
  u16*   xb     = (u16*)  alloc((size_t)NNODES * INDIM * 2);     // 27.5 MB
  u16*   fc2wb  = (u16*)  alloc((size_t)256 * 128 * 2);
  u16*   fc3wb  = (u16*)  alloc((size_t)128 * 64 * 2);
  u16*   fc4wb  = (u16*)  alloc((size_t)64 * OUTDIM * 2);
  u16*   fb1    = (u16*)  alloc(256 * 2);
  u16*   fb2    = (u16*)  alloc(128 * 2);
  u16*   fb3    = (u16*)  alloc(64 * 2);
  u16*   fb4    = (u16*)  alloc(OUTDIM * 2);
  u16*   g1asb  = (u16*)  alloc(4096 * 2);
  u16*   g1adb  = (u16*)  alloc(4096 * 2);
  u16*   g1bb   = (u16*)  alloc(4096 * 2);
  u16*   g2asb  = (u16*)  alloc(64 * 2);
  u16*   g2adb  = (u16*)  alloc(64 * 2);
  u16*   g2bb   = (u16*)  alloc(64 * 2);
  float* bias1  = (float*)alloc((size_t)20480 * 4);
  float* bias2  = (float*)alloc((size_t)N2 * 4);
  int*   flag   = (int*)  alloc(256);
  int*   deg    = (int*)  alloc((size_t)NNODES * 4);
  int*   off    = (int*)  alloc((size_t)(NNODES + 1) * 4);
  int*   cur    = (int*)  alloc((size_t)NNODES * 4);
  int*   esrc   = (int*)  alloc((size_t)NEDGES * 4);
  int*   edst   = (int*)  alloc((size_t)NEDGES * 4);
  float* scT1   = (float*)alloc((size_t)NEDGES * 4 * 4);
  float* esG1   = (float*)alloc((size_t)NNODES * 4 * 4);
  float* edG1   = (float*)alloc((size_t)NNODES * 4 * 4);
  float* scG1   = (float*)alloc((size_t)NEDGES * 4 * 4);
  float* sfG1   = (float*)alloc((size_t)NNODES * 4 * 4);
  float* scT2   = (float*)alloc((size_t)NEDGES * 4);
  float* scG2   = (float*)alloc((size_t)NEDGES * 4);
  float* sfG2   = (float*)alloc((size_t)NNODES * 4);
  float* es2    = (float*)alloc((size_t)NNODES * 4);
  float* ed2    = (float*)alloc((size_t)NNODES * 4);
  float* sn     = (float*)alloc((size_t)NNODES * C2DIM * 4);
  float* f1sum  = (float*)alloc((size_t)NGRAPH * 256 * 4);

  // aliases into yqk for phase C (exactly fills the buffer, no overlap)
  u16* gat = yqk;                               // [NNODES, 4096] compact
  u16* z1  = yqk + (size_t)NNODES * D1;         // [NNODES, 4096] compact

  size_t need = (size_t)(wp - (char*)d_ws);
  if (ws_size < need) {
    fprintf(stderr, "[GATGT kernel] WORKSPACE TOO SMALL ws=%zu need=%zu\n", ws_size, need);
    return;
  }

  // 0) dtype detection
  detect_dtype<<<1, 256, 0, stream>>>((const u16*)x, flag);

  // 1) init + CSR
  zero_kernel<<<27, 256, 0, stream>>>(deg, f1sum);
  count_deg<<<NEDGES / 256, 256, 0, stream>>>(ei, deg);
  scan_deg<<<1, 1024, 0, stream>>>(deg, off, cur);
  scatter_edges<<<NEDGES / 256, 256, 0, stream>>>(ei, cur, esrc, edst);
  pack_bias<<<82, 256, 0, stream>>>(t1_bq, t1_bk, t1_bv, t1_bs,
                                    t2_bq, t2_bk, t2_bv, t2_bs, bias1, bias2, flag);

  // 2) conversions
  conv_any<<<4096, 256, 0, stream>>>(x, xb, (long)NNODES * INDIM, flag);
  {
    SmallConv sc;
    const void* srcs[NSMALL] = { fc2_w, fc3_w, fc4_w, fc1_b, fc2_b, fc3_b, fc4_b,
                                 g1_as, g1_ad, g1_b, g2_as, g2_ad, g2_b };
    u16* dsts[NSMALL] = { fc2wb, fc3wb, fc4wb, fb1, fb2, fb3, fb4,
                          g1asb, g1adb, g1bb, g2asb, g2adb, g2bb };
    int  ns[NSMALL]   = { 256 * 128, 128 * 64, 64 * OUTDIM, 256, 128, 64, OUTDIM,
                          4096, 4096, 4096, 64, 64, 64 };
    for (int i = 0; i < NSMALL; i++) { sc.src[i] = srcs[i]; sc.dst[i] = dsts[i]; sc.n[i] = ns[i]; }
    conv_small<<<NSMALL, 256, 0, stream>>>(sc, flag);
  }

  // 3) Phase A: yqk = xb @ [wq|wk] + [bq|bk]; fused scores+softmax
  transpose_any<<<dim3(128, 64), 256, 0, stream>>>(t1_wq, wtSlab, INDIM, 4096, flag);
  transpose_any<<<dim3(128, 64), 256, 0, stream>>>(t1_wk, wtSlab + (size_t)4096 * INDIM, INDIM, 4096, flag);
  gemm_bt_r3<<<dim3(64, 53), 256, 0, stream>>>(xb, wtSlab, bias1, yqk, NNODES, 8192, INDIM);
  t1_score_sm<<<NNODES, 256, 0, stream>>>(yqk, off, esrc, scT1);

  // 4) Phase B: yqk = xb @ [wv|ws] + [bv|bs]
  transpose_any<<<dim3(128, 64), 256, 0, stream>>>(t1_wv, wtSlab, INDIM, 4096, flag);
  transpose_any<<<dim3(128, 64), 256, 0, stream>>>(t1_ws, wtSlab + (size_t)4096 * INDIM, INDIM, 4096, flag);
  gemm_bt_r3<<<dim3(64, 53), 256, 0, stream>>>(xb, wtSlab, bias1 + 8192, yqk, NNODES, 8192, INDIM);
  t1_agg<<<NNODES, 256, 0, stream>>>(yqk, off, esrc, scT1, h1);

  // 5) Phase C: gat = xb @ g1_w; fused score+softmax; aggregate
  transpose_any<<<dim3(128, 64), 256, 0, stream>>>(g1_w, wtSlab, INDIM, 4096, flag);
  gemm_bt_r3<<<dim3(32, 53), 256, 0, stream>>>(xb, wtSlab, bias1 + 16384, gat, NNODES, 4096, INDIM);
  g1_dots<<<NNODES, 256, 0, stream>>>(gat, g1asb, g1adb, esG1, edG1);
  g1_score_sm<<<NNODES, 256, 0, stream>>>(off, esrc, esG1, edG1, scG1, sfG1);
  g1_agg<<<NNODES, 256, 0, stream>>>(gat, off, esrc, scG1, sfG1, g1bb, z1);

  // 6) merged layer-2 GEMM: y2 = [h1@t2w(+bias) | z1@g2w]; nt==4 epilogue emits es2/ed2
  {
    const void* srcs2[5] = { t2_wq, t2_wk, t2_wv, t2_ws, g2_w };
    for (int s = 0; s < 5; s++)
      transpose_any<<<dim3(2, 128), 256, 0, stream>>>(
          srcs2[s], wt2 + (size_t)s * 64 * D1, D1, 64, flag);
  }
  gemm2_64<<<dim3(5, NNODES / 64), 256, 0, stream>>>(h1, z1, wt2, bias2,
                                                     g2asb, g2adb, y2, es2, ed2);

  // 7) fused T2+G2 scores+softmax, then merged aggregate
  t2g2_score_sm<<<NNODES, 256, 0, stream>>>(y2, off, esrc, es2, ed2, scT2, scG2, sfG2);
  tg2_agg<<<NNODES / 4, 256, 0, stream>>>(y2, off, esrc, scT2, scG2, sfG2, g2bb, sn);

  // 8) MLP head
  fc1_partial<<<128, 256, 0, stream>>>(sn, fc1_w, flag, f1sum);
  fc_tail<<<1, 256, 0, stream>>>(f1sum, fb1, fc2wb, fb2, fc3wb, fb3,
                                 fc4wb, fb4, d_out, flag);
}